// Round 1
// baseline (3222.006 us; speedup 1.0000x reference)
//
#include <hip/hip_runtime.h>
#include <hip/hip_bf16.h>
#include <hip/hip_fp16.h>

using half2_t = __attribute__((ext_vector_type(2))) _Float16;
using half8_t = __attribute__((ext_vector_type(8))) _Float16;
using f32x4   = __attribute__((ext_vector_type(4))) float;

#define B_   64
#define T_   2048
#define D_   256
#define U_   256
#define NG   768      // 3U
#define TC   512      // T-chunk
#define NCHUNK (T_/TC)

typedef const __attribute__((address_space(1))) void* gptr_t;
typedef __attribute__((address_space(3))) void* lptr_t;

__device__ __forceinline__ float fdot2(half2_t a, half2_t b, float c) {
#if __has_builtin(__builtin_amdgcn_fdot2)
  return __builtin_amdgcn_fdot2(a, b, c, false);
#else
  float d;
  asm("v_dot2_f32_f16 %0, %1, %2, %3" : "=v"(d) : "v"(a), "v"(b), "v"(c));
  return d;
#endif
}

// ---------------- conversions ----------------

// x[b, t0..t0+TC, :] (f32) -> xh [64][TC][256] f16, contiguous chunk layout
__global__ void conv_x_chunk(const float* __restrict__ x, _Float16* __restrict__ xh, int t0) {
  size_t idx = ((size_t)blockIdx.x * 256 + threadIdx.x) * 8;   // 8 elems/thread
  int b   = (int)(idx >> 17);        // TC*D = 131072 = 2^17
  int rem = (int)(idx & 131071);
  const float4* p = (const float4*)(x + ((size_t)(b * T_ + t0)) * D_ + rem);
  float4 v0 = p[0], v1 = p[1];
  half8_t o;
  o[0] = (_Float16)v0.x; o[1] = (_Float16)v0.y; o[2] = (_Float16)v0.z; o[3] = (_Float16)v0.w;
  o[4] = (_Float16)v1.x; o[5] = (_Float16)v1.y; o[6] = (_Float16)v1.z; o[7] = (_Float16)v1.w;
  *(half8_t*)(xh + idx) = o;
}

// src [256][768] f32 -> dst [768][256] f16 (transpose + convert)
__global__ void conv_T(const float* __restrict__ src, _Float16* __restrict__ dst) {
  int idx = blockIdx.x * 256 + threadIdx.x;   // 768 blocks -> 196608 exactly
  int d = idx / NG;
  int j = idx - d * NG;
  dst[j * 256 + d] = (_Float16)src[idx];
}

// ---------------- phase 1: xw = x @ kernel  (f16 MFMA) ----------------
// A [M][256] f16 row-major; BT [768][256] f16 (pre-transposed B); C [M][768] f16
#define BM 128
#define BN 128
#define BKH 32   // K halves per step (64 B per row)

__global__ __launch_bounds__(256, 2) void gemm16(
    const _Float16* __restrict__ A,
    const _Float16* __restrict__ BT,
    _Float16* __restrict__ C, int M)
{
  __shared__ alignas(16) _Float16 As[BM * BKH];
  __shared__ alignas(16) _Float16 Bs[BN * BKH];
  const int tid = threadIdx.x, l = tid & 63, w = tid >> 6;
  const int NT = NG / BN;                       // 6
  const int mt = blockIdx.x / NT, nt = blockIdx.x % NT;
  const char* Ab = (const char*)A  + (size_t)mt * BM * 512;   // row stride 512 B
  const char* Bb = (const char*)BT + (size_t)nt * BN * 512;
  const int wm = (w & 1) * 64, wn = (w >> 1) * 64;
  f32x4 acc[4][4] = {};

  for (int kt = 0; kt < 8; ++kt) {
    // stage A tile: 512 x 16B chunks, 2 per thread; XOR-swizzled source (granule ^ (row>>1)&3)
    #pragma unroll
    for (int s = 0; s < 2; ++s) {
      int c = tid + s * 256;
      int row = c >> 2, g = c & 3;
      int gs = g ^ ((row >> 1) & 3);
      __builtin_amdgcn_global_load_lds(
        (gptr_t)(Ab + (size_t)row * 512 + kt * 64 + gs * 16),
        (lptr_t)((char*)As + c * 16), 16, 0, 0);
    }
    #pragma unroll
    for (int s = 0; s < 2; ++s) {
      int c = tid + s * 256;
      int row = c >> 2, g = c & 3;
      int gs = g ^ ((row >> 1) & 3);
      __builtin_amdgcn_global_load_lds(
        (gptr_t)(Bb + (size_t)row * 512 + kt * 64 + gs * 16),
        (lptr_t)((char*)Bs + c * 16), 16, 0, 0);
    }
    __syncthreads();

    half8_t av[4], bv[4];
    #pragma unroll
    for (int m = 0; m < 4; ++m) {
      int row = wm + m * 16 + (l & 15);
      int off = row * 64 + (((l >> 4) ^ ((row >> 1) & 3)) << 4);
      av[m] = *(const half8_t*)((const char*)As + off);
    }
    #pragma unroll
    for (int n = 0; n < 4; ++n) {
      int row = wn + n * 16 + (l & 15);
      int off = row * 64 + (((l >> 4) ^ ((row >> 1) & 3)) << 4);
      bv[n] = *(const half8_t*)((const char*)Bs + off);
    }
    #pragma unroll
    for (int m = 0; m < 4; ++m)
      #pragma unroll
      for (int n = 0; n < 4; ++n)
        acc[m][n] = __builtin_amdgcn_mfma_f32_16x16x32_f16(av[m], bv[n], acc[m][n], 0, 0, 0);
    __syncthreads();
  }

  // epilogue: D col = lane&15, row = (lane>>4)*4 + q  (m89-verified, dtype-independent)
  size_t m0 = (size_t)mt * BM; int n0 = nt * BN;
  #pragma unroll
  for (int m = 0; m < 4; ++m) {
    #pragma unroll
    for (int n = 0; n < 4; ++n) {
      int col = n0 + wn + n * 16 + (l & 15);
      #pragma unroll
      for (int q = 0; q < 4; ++q) {
        size_t row = m0 + wm + m * 16 + ((l >> 4) * 4 + q);
        C[row * NG + col] = (_Float16)acc[m][n][q];
      }
    }
  }
}

// ---------------- phase 2: GRU scan + fused LayerNorm ----------------
// 1 block per batch row; 768 threads; thread j owns gate column j.
// rec column register-resident (128 x f16x2); h broadcast via LDS (f16).
__global__ __launch_bounds__(768, 3) void scan_gru(
    const _Float16* __restrict__ xw,    // [64][TC][768]
    const _Float16* __restrict__ recT,  // [768][256]
    const float* __restrict__ bias,     // [768]
    const float* __restrict__ gamma,
    const float* __restrict__ beta,
    float* __restrict__ out,            // [64][2048][256]
    float* __restrict__ hg,             // [64][256] persisted h
    int t0)
{
  const int b = blockIdx.x, tid = threadIdx.x;
  __shared__ alignas(16) _Float16 hbuf[2][256];
  __shared__ float gbuf[NG];
  __shared__ float red[2][4];

  // load my rec column (recT row tid, 256 f16 = 32 x b128)
  half2_t rv[128];
  {
    const half8_t* rr = (const half8_t*)(recT + (size_t)tid * 256);
    #pragma unroll
    for (int i = 0; i < 32; ++i) {
      half8_t v = rr[i];
      rv[4*i+0] = __builtin_shufflevector(v, v, 0, 1);
      rv[4*i+1] = __builtin_shufflevector(v, v, 2, 3);
      rv[4*i+2] = __builtin_shufflevector(v, v, 4, 5);
      rv[4*i+3] = __builtin_shufflevector(v, v, 6, 7);
    }
  }
  const float bias_j = bias[tid];
  float h = 0.f, gam = 1.f, bet = 0.f;
  if (tid < U_) {
    h = (t0 == 0) ? 0.f : hg[b * U_ + tid];
    gam = gamma[tid]; bet = beta[tid];
    hbuf[0][tid] = (_Float16)h;
  }
  __syncthreads();

  const _Float16* xwp = xw + (size_t)b * TC * NG + tid;
  float* outp = out + ((size_t)b * T_ + t0) * U_;
  _Float16 xc = xwp[0];

  for (int t = 0; t < TC; ++t) {
    _Float16 xn = (_Float16)0.f;
    if (t + 1 < TC) xn = xwp[(size_t)(t + 1) * NG];   // prefetch next step

    float a0 = 0.f, a1 = 0.f, a2 = 0.f, a3 = 0.f;
    const half8_t* hb = (const half8_t*)(&hbuf[t & 1][0]);
    #pragma unroll
    for (int i = 0; i < 32; ++i) {
      half8_t hv = hb[i];
      a0 = fdot2(rv[4*i+0], __builtin_shufflevector(hv, hv, 0, 1), a0);
      a1 = fdot2(rv[4*i+1], __builtin_shufflevector(hv, hv, 2, 3), a1);
      a2 = fdot2(rv[4*i+2], __builtin_shufflevector(hv, hv, 4, 5), a2);
      a3 = fdot2(rv[4*i+3], __builtin_shufflevector(hv, hv, 6, 7), a3);
    }
    float gv = ((a0 + a1) + (a2 + a3)) + (float)xc + bias_j;
    xc = xn;
    if (tid < 512) gv = 1.f / (1.f + __expf(-gv));    // sigmoid for z, r lanes
    gbuf[tid] = gv;
    __syncthreads();                                   // B1

    if (tid < U_) {
      float z  = gv;
      float r  = gbuf[tid + 256];
      float gh = gbuf[tid + 512];
      float y  = r * gh + (1.f - r) * h;
      float th = 2.f / (1.f + __expf(-2.f * y)) - 1.f; // tanh, NaN-safe form
      float hn = (1.f - z) * th + z * h;
      h = hn;
      hbuf[(t & 1) ^ 1][tid] = (_Float16)hn;
      float s = hn, s2 = hn * hn;
      #pragma unroll
      for (int off = 32; off >= 1; off >>= 1) {
        s  += __shfl_xor(s, off);
        s2 += __shfl_xor(s2, off);
      }
      if ((tid & 63) == 0) { red[0][tid >> 6] = s; red[1][tid >> 6] = s2; }
    }
    __syncthreads();                                   // B2

    if (tid < U_) {
      float s  = (red[0][0] + red[0][1]) + (red[0][2] + red[0][3]);
      float s2 = (red[1][0] + red[1][1]) + (red[1][2] + red[1][3]);
      float mu  = s * (1.f / 256.f);
      float var = s2 * (1.f / 256.f) - mu * mu;
      float o = (h - mu) * rsqrtf(var + 1e-6f) * gam + bet;
      outp[(size_t)t * U_ + tid] = o;
    }
  }
  if (tid < U_) hg[b * U_ + tid] = h;
}

// ---------------- launcher ----------------
extern "C" void kernel_launch(void* const* d_in, const int* in_sizes, int n_in,
                              void* d_out, int out_size, void* d_ws, size_t ws_size,
                              hipStream_t stream) {
  const float* x     = (const float*)d_in[0];
  const float* kern  = (const float*)d_in[1];
  const float* rec   = (const float*)d_in[2];
  const float* bias  = (const float*)d_in[3];
  const float* gamma = (const float*)d_in[4];
  const float* beta  = (const float*)d_in[5];
  float* out = (float*)d_out;
  char* ws = (char*)d_ws;

  _Float16* xwc = (_Float16*)(ws);                 // 64*512*768*2 = 50,331,648 B
  _Float16* xhc = (_Float16*)(ws + 50331648);      // 64*512*256*2 = 16,777,216 B
  _Float16* kT  = (_Float16*)(ws + 67108864);      // 393,216 B
  _Float16* rT  = (_Float16*)(ws + 67502080);      // 393,216 B
  float*    hg  = (float*)   (ws + 67895296);      // 65,536 B
  // total ws need: ~64.8 MiB

  conv_T<<<768, 256, 0, stream>>>(kern, kT);
  conv_T<<<768, 256, 0, stream>>>(rec,  rT);

  for (int c = 0; c < NCHUNK; ++c) {
    int t0 = c * TC;
    conv_x_chunk<<<4096, 256, 0, stream>>>(x, xhc, t0);
    gemm16<<<(B_ * TC / BM) * (NG / BN), 256, 0, stream>>>(xhc, kT, xwc, B_ * TC);
    scan_gru<<<B_, 768, 0, stream>>>(xwc, rT, bias, gamma, beta, out, hg, t0);
  }
}